// Round 4
// baseline (533.891 us; speedup 1.0000x reference)
//
#include <hip/hip_runtime.h>
#include <hip/hip_bf16.h>

#define BB 64
#define NN 2048
#define QQ 1024
#define SS 512
#define NCH 4  // n-chunks for shells

__device__ const int PIDX[36] = {
    0, 2, 5, 8, 12, 17, 22, 27, 32, 38, 45, 52, 59, 66, 73, 80,
    88, 97, 106, 115, 124, 133, 142, 151, 160,
    170, 181, 192, 203, 214, 225, 236, 247, 258, 269, 280};

// ---------------- prep: transpose D_eval matrices to [t][q], gather pullback cols, rowsum ----------------
__global__ __launch_bounds__(256) void k_prep(const float* __restrict__ De0,
                                              const float* __restrict__ De1,
                                              const float* __restrict__ De2,
                                              float* __restrict__ Dg0t, float* __restrict__ rs0,
                                              float* __restrict__ Det1, float* __restrict__ Det2) {
    __shared__ float tile[32][33];
    int blk = blockIdx.x, tid = threadIdx.x;
    int r = tid >> 5, c = tid & 31;
    if (blk < 192) {  // D_eval1 [1024,165] -> Det1 [165][1024]
        int tq = blk & 31, tt = blk >> 5;
        int q0 = tq * 32, t0 = tt * 32;
        for (int rr = r; rr < 32; rr += 8) {
            int t = t0 + c;
            tile[rr][c] = (t < 165) ? De1[(q0 + rr) * 165 + t] : 0.f;
        }
        __syncthreads();
        for (int rr = r; rr < 32; rr += 8) {
            int t = t0 + rr;
            if (t < 165) Det1[t * QQ + q0 + c] = tile[c][rr];
        }
    } else if (blk < 288) {  // D_eval2 [1024,84] -> Det2 [84][1024]
        int i = blk - 192;
        int tq = i & 31, tt = i >> 5;
        int q0 = tq * 32, t0 = tt * 32;
        for (int rr = r; rr < 32; rr += 8) {
            int t = t0 + c;
            tile[rr][c] = (t < 84) ? De2[(q0 + rr) * 84 + t] : 0.f;
        }
        __syncthreads();
        for (int rr = r; rr < 32; rr += 8) {
            int t = t0 + rr;
            if (t < 84) Det2[t * QQ + q0 + c] = tile[c][rr];
        }
    } else if (blk < 352) {  // gather D_eval0[:, PIDX] -> Dg0t [36][1024]
        int i = blk - 288;
        int tq = i & 31, tj = i >> 5;
        int q0 = tq * 32, j0 = tj * 32;
        for (int rr = r; rr < 32; rr += 8) {
            int j = j0 + c;
            tile[rr][c] = (j < 36) ? De0[(q0 + rr) * 286 + PIDX[j]] : 0.f;
        }
        __syncthreads();
        for (int rr = r; rr < 32; rr += 8) {
            int j = j0 + rr;
            if (j < 36) Dg0t[j * QQ + q0 + c] = tile[c][rr];
        }
    } else {  // rowsum of D_eval0 over all 286 t
        int q = (blk - 352) * 256 + tid;
        float s = 0.f;
        for (int t = 0; t < 286; t++) s += De0[q * 286 + t];
        rs0[q] = s;
    }
}

// ---------------- shells: partial sums over n-chunk; pbuf[zc][shell][b][s] ----------------
__global__ __launch_bounds__(256) void k_shells(const float* __restrict__ x,
                                                const float* __restrict__ dirs,
                                                float* __restrict__ pbuf) {
    __shared__ float4 lx[NN / NCH];
    int b = blockIdx.x, shell = blockIdx.y, zc = blockIdx.z;
    const float* xb = x + ((size_t)b * NN + zc * (NN / NCH)) * 3;
    for (int n = threadIdx.x; n < NN / NCH; n += 256) {
        float X = xb[n * 3 + 0];
        float Y = xb[n * 3 + 1];
        float Z = xb[n * 3 + 2];
        lx[n] = make_float4(X, Y, Z, X * X + Y * Y + Z * Z);
    }
    __syncthreads();
    float r = (shell == 0) ? 0.4f : ((shell == 1) ? 0.8f : 1.2f);
    const float KL = 18.033688011112042f;  // log2(e)/SIGMA2, SIGMA2=0.08
    int s0 = threadIdx.x, s1 = threadIdx.x + 256;
    float cx0 = r * dirs[(shell * SS + s0) * 3 + 0];
    float cy0 = r * dirs[(shell * SS + s0) * 3 + 1];
    float cz0 = r * dirs[(shell * SS + s0) * 3 + 2];
    float cx1 = r * dirs[(shell * SS + s1) * 3 + 0];
    float cy1 = r * dirs[(shell * SS + s1) * 3 + 1];
    float cz1 = r * dirs[(shell * SS + s1) * 3 + 2];
    float base0 = -KL * (cx0 * cx0 + cy0 * cy0 + cz0 * cz0);
    float base1 = -KL * (cx1 * cx1 + cy1 * cy1 + cz1 * cz1);
    float cxs0 = 2.f * KL * cx0, cys0 = 2.f * KL * cy0, czs0 = 2.f * KL * cz0;
    float cxs1 = 2.f * KL * cx1, cys1 = 2.f * KL * cy1, czs1 = 2.f * KL * cz1;
    float a0 = 0.f, a1 = 0.f;
#pragma unroll 4
    for (int n = 0; n < NN / NCH; n++) {
        float4 p = lx[n];
        float t = fmaf(-KL, p.w, 0.f);
        a0 += exp2f(fmaf(cxs0, p.x, fmaf(cys0, p.y, fmaf(czs0, p.z, t + base0))));
        a1 += exp2f(fmaf(cxs1, p.x, fmaf(cys1, p.y, fmaf(czs1, p.z, t + base1))));
    }
    float* o = pbuf + ((size_t)(zc * 3 + shell) * BB + b) * SS;
    o[s0] = a0;
    o[s1] = a1;
}

// ---------------- eval0: chunk-reduce + SH project + mix(W0) + sparse Wigner eval + fused stats ----------------
__global__ __launch_bounds__(256) void k_eval0(const float* __restrict__ pbuf,
                                               const float* __restrict__ A_sh,
                                               const float* __restrict__ W0, const float* __restrict__ b0,
                                               const float* __restrict__ Dg0t, const float* __restrict__ rs0,
                                               float* __restrict__ yq, float* __restrict__ stats) {
    __shared__ float lf[3][SS];
    __shared__ float lshp[216];
    __shared__ float lsh[36][3];
    __shared__ float lm[36][16];
    __shared__ float lred[4][32];
    int qc = blockIdx.x, b = blockIdx.y, tid = threadIdx.x;
    for (int i = tid; i < 3 * SS; i += 256) {
        int c = i / SS, s = i % SS;
        float v = 0.f;
#pragma unroll
        for (int zc = 0; zc < NCH; zc++) v += pbuf[((size_t)(zc * 3 + c) * BB + b) * SS + s];
        lf[c][s] = v * (1.0f / NN);
    }
    __syncthreads();
    if (tid < 216) {  // (j, c, s-half) partial SH projection
        int j = tid / 6, rm = tid % 6, c = rm >> 1, h = rm & 1;
        const float* As = A_sh + j * SS + h * 256;
        const float* lfp = &lf[c][h * 256];
        float a = 0.f;
        for (int s = 0; s < 256; s++) a = fmaf(lfp[s], As[s], a);
        lshp[tid] = a;
    }
    __syncthreads();
    if (tid < 108) {
        int j = tid / 3, c = tid % 3;
        lsh[j][c] = lshp[j * 6 + c * 2] + lshp[j * 6 + c * 2 + 1];
    }
    __syncthreads();
    for (int e = tid; e < 576; e += 256) {
        int j = e >> 4, u = e & 15;
        float m = 0.f;
#pragma unroll
        for (int c = 0; c < 3; c++) m = fmaf(lsh[j][c], W0[c * 16 + u], m);
        lm[j][u] = m;
    }
    __syncthreads();
    int q = qc * 256 + tid;
    float acc[16];
#pragma unroll
    for (int u = 0; u < 16; u++) acc[u] = 0.f;
#pragma unroll 4
    for (int j = 0; j < 36; j++) {
        float d = Dg0t[j * QQ + q];
#pragma unroll
        for (int u = 0; u < 16; u++) acc[u] = fmaf(d, lm[j][u], acc[u]);
    }
    float rb = rs0[q];
#pragma unroll
    for (int u = 0; u < 16; u++) acc[u] = fmaf(b0[u], rb, acc[u]);
#pragma unroll
    for (int u = 0; u < 16; u++) yq[((size_t)b * 16 + u) * QQ + q] = acc[u];
    // fused stats
    int lane = tid & 63, w = tid >> 6;
#pragma unroll
    for (int u = 0; u < 16; u++) {
        float v = acc[u], v2 = acc[u] * acc[u];
#pragma unroll
        for (int o = 32; o > 0; o >>= 1) {
            v += __shfl_xor(v, o, 64);
            v2 += __shfl_xor(v2, o, 64);
        }
        if (lane == 0) { lred[w][u] = v; lred[w][16 + u] = v2; }
    }
    __syncthreads();
    if (tid < 32) atomicAdd(&stats[tid], lred[0][tid] + lred[1][tid] + lred[2][tid] + lred[3][tid]);
}

// ---------------- generic eval: mix(W,b) fused + Wigner eval + fused stats ----------------
template <int TT, int CC, int UU>
__global__ __launch_bounds__(256) void k_eval(const float* __restrict__ yt,
                                              const float* __restrict__ W, const float* __restrict__ bias,
                                              const float* __restrict__ Det,
                                              float* __restrict__ yq, float* __restrict__ stats) {
    __shared__ float lyt[TT * CC];
    __shared__ float lym[TT * UU];
    __shared__ float lred[4][2 * UU];
    int qc = blockIdx.x, b = blockIdx.y, tid = threadIdx.x;
    for (int i = tid; i < TT * CC; i += 256) lyt[i] = yt[(size_t)b * TT * CC + i];
    __syncthreads();
    for (int e = tid; e < TT * UU; e += 256) {
        int t = e / UU, u = e % UU;
        float m = bias[u];
#pragma unroll
        for (int c = 0; c < CC; c++) m = fmaf(lyt[t * CC + c], W[c * UU + u], m);
        lym[e] = m;
    }
    __syncthreads();
    int q = qc * 256 + tid;
    float acc[UU];
#pragma unroll
    for (int u = 0; u < UU; u++) acc[u] = 0.f;
#pragma unroll 4
    for (int t = 0; t < TT; t++) {
        float d = Det[t * QQ + q];
#pragma unroll
        for (int u = 0; u < UU; u++) acc[u] = fmaf(d, lym[t * UU + u], acc[u]);
    }
#pragma unroll
    for (int u = 0; u < UU; u++) yq[((size_t)b * UU + u) * QQ + q] = acc[u];
    // fused stats
    int lane = tid & 63, w = tid >> 6;
#pragma unroll
    for (int u = 0; u < UU; u++) {
        float v = acc[u], v2 = acc[u] * acc[u];
#pragma unroll
        for (int o = 32; o > 0; o >>= 1) {
            v += __shfl_xor(v, o, 64);
            v2 += __shfl_xor(v2, o, 64);
        }
        if (lane == 0) { lred[w][u] = v; lred[w][UU + u] = v2; }
    }
    __syncthreads();
    if (tid < 2 * UU)
        atomicAdd(&stats[tid], lred[0][tid] + lred[1][tid] + lred[2][tid] + lred[3][tid]);
}

// ---------------- generic coef: BN finalize + LeakyReLU fused + Wigner coeff projection ----------------
// LDS layout [qq][u] so the inner loop reads NU consecutive u per thread (b128 for NU=4).
template <int TT, int UU>
__global__ __launch_bounds__(256) void k_coef(const float* __restrict__ yq,
                                              const float* __restrict__ Dc,
                                              const float* __restrict__ stats,
                                              const float* __restrict__ g, const float* __restrict__ be,
                                              float* __restrict__ out) {
    constexpr int NU = UU / 16;
    constexpr int RP = UU + 4;  // row pad keeps 16B alignment
    __shared__ float lY[128][RP];
    __shared__ float lD[16][132];
    __shared__ float lsu[UU], ltu[UU];
    int tc = blockIdx.x, b = blockIdx.y, tid = threadIdx.x;
    if (tid < UU) {
        const float inv = 1.0f / (BB * QQ);
        float m = stats[tid] * inv;
        float var = stats[UU + tid] * inv - m * m;
        float s = g[tid] * rsqrtf(fmaxf(var, 0.f) + 1e-3f);
        lsu[tid] = s;
        ltu[tid] = be[tid] - m * s;
    }
    __syncthreads();
    int tl = tid >> 4, ul = tid & 15, ub = ul * NU;
    int t = tc * 16 + tl;
    float acc[NU];
#pragma unroll
    for (int i = 0; i < NU; i++) acc[i] = 0.f;
    for (int kc = 0; kc < 8; kc++) {
        for (int i = tid; i < UU * 128; i += 256) {
            int u = i >> 7, qq = i & 127;
            float v = yq[((size_t)b * UU + u) * QQ + kc * 128 + qq];
            v = fmaf(v, lsu[u], ltu[u]);
            lY[qq][u] = (v > 0.f) ? v : 0.3f * v;
        }
        for (int i = tid; i < 16 * 128; i += 256) {
            int t_l = i >> 7, qq = i & 127;
            int tg = tc * 16 + t_l;
            lD[t_l][qq] = (tg < TT) ? Dc[(size_t)tg * QQ + kc * 128 + qq] : 0.f;
        }
        __syncthreads();
#pragma unroll 4
        for (int qq = 0; qq < 128; qq++) {
            float d = lD[tl][qq];
#pragma unroll
            for (int iu = 0; iu < NU; iu++) acc[iu] = fmaf(d, lY[qq][ub + iu], acc[iu]);
        }
        __syncthreads();
    }
    if (t < TT) {
#pragma unroll
        for (int iu = 0; iu < NU; iu++)
            out[((size_t)b * TT + t) * UU + ub + iu] = acc[iu];
    }
}

// ---------------- degree-wise norms -> ht0 [256 feat][64 batch] ----------------
__global__ __launch_bounds__(256) void k_norms(const float* __restrict__ yt3, float* __restrict__ ht0) {
    int b = blockIdx.x, tid = threadIdx.x;
    int blk = tid >> 6, u = tid & 63;
    const int offs[4] = {0, 1, 10, 35};
    const int ends[4] = {1, 10, 35, 84};
    float a = 0.f;
    for (int t = offs[blk]; t < ends[blk]; t++) {
        float v = yt3[((size_t)b * 84 + t) * 64 + u];
        a = fmaf(v, v, a);
    }
    ht0[(blk * 64 + u) * BB + b] = sqrtf(fmaxf(a, 0.f));
}

// ---------------- fc + batch-BN + relu (lane = batch, wave = feature), LDS reductions ----------------
template <int K, int J>
__global__ __launch_bounds__(512) void k_fc(const float* __restrict__ in, const float* __restrict__ W,
                                            const float* __restrict__ bias, const float* __restrict__ g,
                                            const float* __restrict__ be, float* __restrict__ out) {
    __shared__ float sm1[512];
    __shared__ float sm2[512];
    int tid = threadIdx.x;
    int b = tid & 63;
    int w = tid >> 6;
    int j = blockIdx.x * 8 + w;
    float acc = bias[j];
#pragma unroll 8
    for (int k = 0; k < K; k++) acc = fmaf(in[k * BB + b], W[k * J + j], acc);
    sm1[tid] = acc;
    sm2[tid] = acc * acc;
    __syncthreads();
    for (int o = 32; o > 0; o >>= 1) {
        if (b < o) { sm1[tid] += sm1[tid + o]; sm2[tid] += sm2[tid + o]; }
        __syncthreads();
    }
    float m = sm1[w * 64] * (1.0f / 64.f);
    float var = sm2[w * 64] * (1.0f / 64.f) - m * m;
    float sc = g[j] * rsqrtf(fmaxf(var, 0.f) + 1e-3f);
    float v = (acc - m) * sc + be[j];
    out[j * BB + b] = fmaxf(v, 0.f);
}

// ---------------- output layer + softmax (LDS reductions) ----------------
__global__ __launch_bounds__(64) void k_out(const float* __restrict__ ht2, const float* __restrict__ Wout,
                                            const float* __restrict__ bout, float* __restrict__ outp) {
    __shared__ float sm[64];
    int b = blockIdx.x, o = threadIdx.x;
    float acc = 0.f;
    if (o < 40) {
        acc = bout[o];
        for (int k = 0; k < 256; k++) acc = fmaf(ht2[k * BB + b], Wout[k * 40 + o], acc);
    }
    sm[o] = (o < 40) ? acc : -3.0e38f;
    __syncthreads();
    for (int s = 32; s > 0; s >>= 1) {
        if (o < s) sm[o] = fmaxf(sm[o], sm[o + s]);
        __syncthreads();
    }
    float m = sm[0];
    __syncthreads();
    const float L2E = 1.4426950408889634f;
    float e = (o < 40) ? exp2f((acc - m) * L2E) : 0.f;
    sm[o] = e;
    __syncthreads();
    for (int s = 32; s > 0; s >>= 1) {
        if (o < s) sm[o] += sm[o + s];
        __syncthreads();
    }
    if (o < 40) outp[b * 40 + o] = e / sm[0];
}

// ---------------- workspace layout (float offsets) ----------------
#define OFF_PBUF 0          // 4*3*64*512   = 393216
#define OFF_DG0T 393216     // 36*1024      = 36864
#define OFF_RS0 430080      // 1024
#define OFF_DET1 431104     // 165*1024     = 168960
#define OFF_DET2 600064     // 84*1024      = 86016
#define OFF_YQ 686080       // 64*64*1024   = 4194304
#define OFF_YT1 4880384     // 64*165*16    = 168960
#define OFF_YT2 5049344     // 64*84*32     = 172032
#define OFF_YT3 5221376     // 64*84*64     = 344064
#define OFF_HT0 5565440     // 256*64
#define OFF_HT1 5581824     // 512*64
#define OFF_HT2 5614592     // 256*64
#define OFF_STATS 5630976   // 224

extern "C" void kernel_launch(void* const* d_in, const int* in_sizes, int n_in,
                              void* d_out, int out_size, void* d_ws, size_t ws_size,
                              hipStream_t stream) {
    const float* x = (const float*)d_in[0];
    const float* shell_dirs = (const float*)d_in[1];
    const float* A_sh = (const float*)d_in[2];
    const float* D_eval0 = (const float*)d_in[3];
    const float* D_eval1 = (const float*)d_in[4];
    const float* D_eval2 = (const float*)d_in[5];
    const float* D_coef1 = (const float*)d_in[6];
    const float* D_coef2 = (const float*)d_in[7];
    const float* D_coef_last = (const float*)d_in[8];
    const float* W0 = (const float*)d_in[9];
    const float* b0 = (const float*)d_in[10];
    const float* W1 = (const float*)d_in[11];
    const float* b1 = (const float*)d_in[12];
    const float* W2 = (const float*)d_in[13];
    const float* b2 = (const float*)d_in[14];
    const float* g0 = (const float*)d_in[15];
    const float* be0 = (const float*)d_in[16];
    const float* g1 = (const float*)d_in[17];
    const float* be1 = (const float*)d_in[18];
    const float* g2 = (const float*)d_in[19];
    const float* be2 = (const float*)d_in[20];
    const float* Wfc1 = (const float*)d_in[21];
    const float* bfc1 = (const float*)d_in[22];
    const float* gfc1 = (const float*)d_in[23];
    const float* befc1 = (const float*)d_in[24];
    const float* Wfc2 = (const float*)d_in[25];
    const float* bfc2 = (const float*)d_in[26];
    const float* gfc2 = (const float*)d_in[27];
    const float* befc2 = (const float*)d_in[28];
    const float* Wout = (const float*)d_in[29];
    const float* bout = (const float*)d_in[30];
    float* out = (float*)d_out;

    float* ws = (float*)d_ws;
    float* pbuf = ws + OFF_PBUF;
    float* Dg0t = ws + OFF_DG0T;
    float* rs0 = ws + OFF_RS0;
    float* Det1 = ws + OFF_DET1;
    float* Det2 = ws + OFF_DET2;
    float* yq = ws + OFF_YQ;
    float* yt1 = ws + OFF_YT1;
    float* yt2 = ws + OFF_YT2;
    float* yt3 = ws + OFF_YT3;
    float* ht0 = ws + OFF_HT0;
    float* ht1 = ws + OFF_HT1;
    float* ht2 = ws + OFF_HT2;
    float* stats = ws + OFF_STATS;
    float* stats0 = stats;       // 32
    float* stats1 = stats + 32;  // 64
    float* stats2 = stats + 96;  // 128

    hipMemsetAsync(stats, 0, 224 * sizeof(float), stream);

    k_prep<<<356, 256, 0, stream>>>(D_eval0, D_eval1, D_eval2, Dg0t, rs0, Det1, Det2);
    k_shells<<<dim3(BB, 3, NCH), 256, 0, stream>>>(x, shell_dirs, pbuf);
    k_eval0<<<dim3(4, BB), 256, 0, stream>>>(pbuf, A_sh, W0, b0, Dg0t, rs0, yq, stats0);
    k_coef<165, 16><<<dim3(11, BB), 256, 0, stream>>>(yq, D_coef1, stats0, g0, be0, yt1);
    k_eval<165, 16, 32><<<dim3(4, BB), 256, 0, stream>>>(yt1, W1, b1, Det1, yq, stats1);
    k_coef<84, 32><<<dim3(6, BB), 256, 0, stream>>>(yq, D_coef2, stats1, g1, be1, yt2);
    k_eval<84, 32, 64><<<dim3(4, BB), 256, 0, stream>>>(yt2, W2, b2, Det2, yq, stats2);
    k_coef<84, 64><<<dim3(6, BB), 256, 0, stream>>>(yq, D_coef_last, stats2, g2, be2, yt3);
    k_norms<<<BB, 256, 0, stream>>>(yt3, ht0);
    k_fc<256, 512><<<64, 512, 0, stream>>>(ht0, Wfc1, bfc1, gfc1, befc1, ht1);
    k_fc<512, 256><<<32, 512, 0, stream>>>(ht1, Wfc2, bfc2, gfc2, befc2, ht2);
    k_out<<<BB, 64, 0, stream>>>(ht2, Wout, bout, out);
}

// Round 5
// 461.775 us; speedup vs baseline: 1.1562x; 1.1562x over previous
//
#include <hip/hip_runtime.h>
#include <hip/hip_bf16.h>

#define BB 64
#define NN 2048
#define QQ 1024
#define SS 512
#define NCH 4  // n-chunks for shells

__device__ const int PIDX[36] = {
    0, 2, 5, 8, 12, 17, 22, 27, 32, 38, 45, 52, 59, 66, 73, 80,
    88, 97, 106, 115, 124, 133, 142, 151, 160,
    170, 181, 192, 203, 214, 225, 236, 247, 258, 269, 280};

// ---------------- prep: transpose D_eval matrices to [t][q], gather pullback cols, rowsum, zero stats ----------------
__global__ __launch_bounds__(256) void k_prep(const float* __restrict__ De0,
                                              const float* __restrict__ De1,
                                              const float* __restrict__ De2,
                                              float* __restrict__ Dg0t, float* __restrict__ rs0,
                                              float* __restrict__ Det1, float* __restrict__ Det2,
                                              float* __restrict__ stats) {
    __shared__ float tile[32][33];
    int blk = blockIdx.x, tid = threadIdx.x;
    int r = tid >> 5, c = tid & 31;
    if (blk < 192) {  // D_eval1 [1024,165] -> Det1 [165][1024]
        int tq = blk & 31, tt = blk >> 5;
        int q0 = tq * 32, t0 = tt * 32;
        for (int rr = r; rr < 32; rr += 8) {
            int t = t0 + c;
            tile[rr][c] = (t < 165) ? De1[(q0 + rr) * 165 + t] : 0.f;
        }
        __syncthreads();
        for (int rr = r; rr < 32; rr += 8) {
            int t = t0 + rr;
            if (t < 165) Det1[t * QQ + q0 + c] = tile[c][rr];
        }
    } else if (blk < 288) {  // D_eval2 [1024,84] -> Det2 [84][1024]
        int i = blk - 192;
        int tq = i & 31, tt = i >> 5;
        int q0 = tq * 32, t0 = tt * 32;
        for (int rr = r; rr < 32; rr += 8) {
            int t = t0 + c;
            tile[rr][c] = (t < 84) ? De2[(q0 + rr) * 84 + t] : 0.f;
        }
        __syncthreads();
        for (int rr = r; rr < 32; rr += 8) {
            int t = t0 + rr;
            if (t < 84) Det2[t * QQ + q0 + c] = tile[c][rr];
        }
    } else if (blk < 352) {  // gather D_eval0[:, PIDX] -> Dg0t [36][1024]
        int i = blk - 288;
        int tq = i & 31, tj = i >> 5;
        int q0 = tq * 32, j0 = tj * 32;
        for (int rr = r; rr < 32; rr += 8) {
            int j = j0 + c;
            tile[rr][c] = (j < 36) ? De0[(q0 + rr) * 286 + PIDX[j]] : 0.f;
        }
        __syncthreads();
        for (int rr = r; rr < 32; rr += 8) {
            int j = j0 + rr;
            if (j < 36) Dg0t[j * QQ + q0 + c] = tile[c][rr];
        }
    } else if (blk < 356) {  // rowsum of D_eval0 over all 286 t
        int q = (blk - 352) * 256 + tid;
        float s = 0.f;
        for (int t = 0; t < 286; t++) s += De0[q * 286 + t];
        rs0[q] = s;
    } else {  // zero the BN-stats accumulators
        if (tid < 224) stats[tid] = 0.f;
    }
}

// ---------------- shells: partial sums over n-chunk; pbuf[zc][shell][b][s] ----------------
__global__ __launch_bounds__(256) void k_shells(const float* __restrict__ x,
                                                const float* __restrict__ dirs,
                                                float* __restrict__ pbuf) {
    __shared__ float4 lx[NN / NCH];
    int b = blockIdx.x, shell = blockIdx.y, zc = blockIdx.z;
    const float KL = 18.033688011112042f;  // log2(e)/SIGMA2, SIGMA2=0.08
    const float* xb = x + ((size_t)b * NN + zc * (NN / NCH)) * 3;
    for (int n = threadIdx.x; n < NN / NCH; n += 256) {
        float X = xb[n * 3 + 0];
        float Y = xb[n * 3 + 1];
        float Z = xb[n * 3 + 2];
        // fold -KL*|x|^2 into the staged w
        lx[n] = make_float4(X, Y, Z, -KL * (X * X + Y * Y + Z * Z));
    }
    __syncthreads();
    float r = (shell == 0) ? 0.4f : ((shell == 1) ? 0.8f : 1.2f);
    int s0 = threadIdx.x, s1 = threadIdx.x + 256;
    float cx0 = r * dirs[(shell * SS + s0) * 3 + 0];
    float cy0 = r * dirs[(shell * SS + s0) * 3 + 1];
    float cz0 = r * dirs[(shell * SS + s0) * 3 + 2];
    float cx1 = r * dirs[(shell * SS + s1) * 3 + 0];
    float cy1 = r * dirs[(shell * SS + s1) * 3 + 1];
    float cz1 = r * dirs[(shell * SS + s1) * 3 + 2];
    float base0 = -KL * (cx0 * cx0 + cy0 * cy0 + cz0 * cz0);
    float base1 = -KL * (cx1 * cx1 + cy1 * cy1 + cz1 * cz1);
    float cxs0 = 2.f * KL * cx0, cys0 = 2.f * KL * cy0, czs0 = 2.f * KL * cz0;
    float cxs1 = 2.f * KL * cx1, cys1 = 2.f * KL * cy1, czs1 = 2.f * KL * cz1;
    float a0 = 0.f, a1 = 0.f;
#pragma unroll 8
    for (int n = 0; n < NN / NCH; n++) {
        float4 p = lx[n];
        // raw v_exp_f32: args always <= 0, HW flush-to-zero for large-negative is exact here
        a0 += __builtin_amdgcn_exp2f(fmaf(cxs0, p.x, fmaf(cys0, p.y, fmaf(czs0, p.z, p.w + base0))));
        a1 += __builtin_amdgcn_exp2f(fmaf(cxs1, p.x, fmaf(cys1, p.y, fmaf(czs1, p.z, p.w + base1))));
    }
    float* o = pbuf + ((size_t)(zc * 3 + shell) * BB + b) * SS;
    o[s0] = a0;
    o[s1] = a1;
}

// ---------------- eval0: chunk-reduce + SH project + mix(W0) + sparse Wigner eval + fused stats ----------------
__global__ __launch_bounds__(256) void k_eval0(const float* __restrict__ pbuf,
                                               const float* __restrict__ A_sh,
                                               const float* __restrict__ W0, const float* __restrict__ b0,
                                               const float* __restrict__ Dg0t, const float* __restrict__ rs0,
                                               float* __restrict__ yq, float* __restrict__ stats) {
    __shared__ float lf[3][SS];
    __shared__ float lshp[216];
    __shared__ float lsh[36][3];
    __shared__ float lm[36][16];
    __shared__ float lred[4][32];
    int qc = blockIdx.x, b = blockIdx.y, tid = threadIdx.x;
    for (int i = tid; i < 3 * SS; i += 256) {
        int c = i / SS, s = i % SS;
        float v = 0.f;
#pragma unroll
        for (int zc = 0; zc < NCH; zc++) v += pbuf[((size_t)(zc * 3 + c) * BB + b) * SS + s];
        lf[c][s] = v * (1.0f / NN);
    }
    __syncthreads();
    if (tid < 216) {  // (j, c, s-half) partial SH projection
        int j = tid / 6, rm = tid % 6, c = rm >> 1, h = rm & 1;
        const float* As = A_sh + j * SS + h * 256;
        const float* lfp = &lf[c][h * 256];
        float a = 0.f;
        for (int s = 0; s < 256; s++) a = fmaf(lfp[s], As[s], a);
        lshp[tid] = a;
    }
    __syncthreads();
    if (tid < 108) {
        int j = tid / 3, c = tid % 3;
        lsh[j][c] = lshp[j * 6 + c * 2] + lshp[j * 6 + c * 2 + 1];
    }
    __syncthreads();
    for (int e = tid; e < 576; e += 256) {
        int j = e >> 4, u = e & 15;
        float m = 0.f;
#pragma unroll
        for (int c = 0; c < 3; c++) m = fmaf(lsh[j][c], W0[c * 16 + u], m);
        lm[j][u] = m;
    }
    __syncthreads();
    int q = qc * 256 + tid;
    float acc[16];
#pragma unroll
    for (int u = 0; u < 16; u++) acc[u] = 0.f;
#pragma unroll 4
    for (int j = 0; j < 36; j++) {
        float d = Dg0t[j * QQ + q];
#pragma unroll
        for (int u = 0; u < 16; u++) acc[u] = fmaf(d, lm[j][u], acc[u]);
    }
    float rb = rs0[q];
#pragma unroll
    for (int u = 0; u < 16; u++) acc[u] = fmaf(b0[u], rb, acc[u]);
#pragma unroll
    for (int u = 0; u < 16; u++) yq[((size_t)b * 16 + u) * QQ + q] = acc[u];
    // fused stats
    int lane = tid & 63, w = tid >> 6;
#pragma unroll
    for (int u = 0; u < 16; u++) {
        float v = acc[u], v2 = acc[u] * acc[u];
#pragma unroll
        for (int o = 32; o > 0; o >>= 1) {
            v += __shfl_xor(v, o, 64);
            v2 += __shfl_xor(v2, o, 64);
        }
        if (lane == 0) { lred[w][u] = v; lred[w][16 + u] = v2; }
    }
    __syncthreads();
    if (tid < 32) atomicAdd(&stats[tid], lred[0][tid] + lred[1][tid] + lred[2][tid] + lred[3][tid]);
}

// ---------------- generic eval: mix(W,b) fused + Wigner eval + fused stats ----------------
// u-split: blockIdx.z picks a 16-wide u slice for better occupancy + fewer LDS reads per thread.
template <int TT, int CC, int UU>
__global__ __launch_bounds__(256) void k_eval(const float* __restrict__ yt,
                                              const float* __restrict__ W, const float* __restrict__ bias,
                                              const float* __restrict__ Det,
                                              float* __restrict__ yq, float* __restrict__ stats) {
    __shared__ float lyt[TT * CC];
    __shared__ float lym[TT * 16];
    __shared__ float lred[4][32];
    int qc = blockIdx.x, b = blockIdx.y, uz = blockIdx.z * 16, tid = threadIdx.x;
    for (int i = tid; i < TT * CC; i += 256) lyt[i] = yt[(size_t)b * TT * CC + i];
    __syncthreads();
    for (int e = tid; e < TT * 16; e += 256) {
        int t = e >> 4, ul = e & 15, u = uz + ul;
        float m = bias[u];
#pragma unroll
        for (int c = 0; c < CC; c++) m = fmaf(lyt[t * CC + c], W[c * UU + u], m);
        lym[e] = m;
    }
    __syncthreads();
    int q = qc * 256 + tid;
    float acc[16];
#pragma unroll
    for (int u = 0; u < 16; u++) acc[u] = 0.f;
#pragma unroll 4
    for (int t = 0; t < TT; t++) {
        float d = Det[t * QQ + q];
#pragma unroll
        for (int u = 0; u < 16; u++) acc[u] = fmaf(d, lym[t * 16 + u], acc[u]);
    }
#pragma unroll
    for (int u = 0; u < 16; u++) yq[((size_t)b * UU + uz + u) * QQ + q] = acc[u];
    // fused stats for this u-slice
    int lane = tid & 63, w = tid >> 6;
#pragma unroll
    for (int u = 0; u < 16; u++) {
        float v = acc[u], v2 = acc[u] * acc[u];
#pragma unroll
        for (int o = 32; o > 0; o >>= 1) {
            v += __shfl_xor(v, o, 64);
            v2 += __shfl_xor(v2, o, 64);
        }
        if (lane == 0) { lred[w][u] = v; lred[w][16 + u] = v2; }
    }
    __syncthreads();
    if (tid < 32) {
        float s = lred[0][tid] + lred[1][tid] + lred[2][tid] + lred[3][tid];
        int idx = (tid < 16) ? (uz + tid) : (UU + uz + tid - 16);
        atomicAdd(&stats[idx], s);
    }
}

// ---------------- generic coef: BN finalize + LeakyReLU fused + Wigner coeff projection ----------------
// LDS layout [qq][u] so the inner loop reads NU consecutive u per thread (b128 for NU=4).
template <int TT, int UU>
__global__ __launch_bounds__(256) void k_coef(const float* __restrict__ yq,
                                              const float* __restrict__ Dc,
                                              const float* __restrict__ stats,
                                              const float* __restrict__ g, const float* __restrict__ be,
                                              float* __restrict__ out) {
    constexpr int NU = UU / 16;
    constexpr int RP = UU + 4;  // row pad keeps 16B alignment
    __shared__ float lY[128][RP];
    __shared__ float lD[16][132];
    __shared__ float lsu[UU], ltu[UU];
    int tc = blockIdx.x, b = blockIdx.y, tid = threadIdx.x;
    if (tid < UU) {
        const float inv = 1.0f / (BB * QQ);
        float m = stats[tid] * inv;
        float var = stats[UU + tid] * inv - m * m;
        float s = g[tid] * rsqrtf(fmaxf(var, 0.f) + 1e-3f);
        lsu[tid] = s;
        ltu[tid] = be[tid] - m * s;
    }
    __syncthreads();
    int tl = tid >> 4, ul = tid & 15, ub = ul * NU;
    int t = tc * 16 + tl;
    float acc[NU];
#pragma unroll
    for (int i = 0; i < NU; i++) acc[i] = 0.f;
    for (int kc = 0; kc < 8; kc++) {
        for (int i = tid; i < UU * 128; i += 256) {
            int u = i >> 7, qq = i & 127;
            float v = yq[((size_t)b * UU + u) * QQ + kc * 128 + qq];
            v = fmaf(v, lsu[u], ltu[u]);
            lY[qq][u] = (v > 0.f) ? v : 0.3f * v;
        }
        for (int i = tid; i < 16 * 128; i += 256) {
            int t_l = i >> 7, qq = i & 127;
            int tg = tc * 16 + t_l;
            lD[t_l][qq] = (tg < TT) ? Dc[(size_t)tg * QQ + kc * 128 + qq] : 0.f;
        }
        __syncthreads();
#pragma unroll 4
        for (int qq = 0; qq < 128; qq++) {
            float d = lD[tl][qq];
#pragma unroll
            for (int iu = 0; iu < NU; iu++) acc[iu] = fmaf(d, lY[qq][ub + iu], acc[iu]);
        }
        __syncthreads();
    }
    if (t < TT) {
#pragma unroll
        for (int iu = 0; iu < NU; iu++)
            out[((size_t)b * TT + t) * UU + ub + iu] = acc[iu];
    }
}

// ---------------- degree-wise norms -> ht0 [256 feat][64 batch] ----------------
__global__ __launch_bounds__(256) void k_norms(const float* __restrict__ yt3, float* __restrict__ ht0) {
    int b = blockIdx.x, tid = threadIdx.x;
    int blk = tid >> 6, u = tid & 63;
    const int offs[4] = {0, 1, 10, 35};
    const int ends[4] = {1, 10, 35, 84};
    float a = 0.f;
    for (int t = offs[blk]; t < ends[blk]; t++) {
        float v = yt3[((size_t)b * 84 + t) * 64 + u];
        a = fmaf(v, v, a);
    }
    ht0[(blk * 64 + u) * BB + b] = sqrtf(fmaxf(a, 0.f));
}

// ---------------- fc + batch-BN + relu (lane = batch, wave = feature), LDS reductions ----------------
template <int K, int J>
__global__ __launch_bounds__(512) void k_fc(const float* __restrict__ in, const float* __restrict__ W,
                                            const float* __restrict__ bias, const float* __restrict__ g,
                                            const float* __restrict__ be, float* __restrict__ out) {
    __shared__ float sm1[512];
    __shared__ float sm2[512];
    int tid = threadIdx.x;
    int b = tid & 63;
    int w = tid >> 6;
    int j = blockIdx.x * 8 + w;
    float acc = bias[j];
#pragma unroll 8
    for (int k = 0; k < K; k++) acc = fmaf(in[k * BB + b], W[k * J + j], acc);
    sm1[tid] = acc;
    sm2[tid] = acc * acc;
    __syncthreads();
    for (int o = 32; o > 0; o >>= 1) {
        if (b < o) { sm1[tid] += sm1[tid + o]; sm2[tid] += sm2[tid + o]; }
        __syncthreads();
    }
    float m = sm1[w * 64] * (1.0f / 64.f);
    float var = sm2[w * 64] * (1.0f / 64.f) - m * m;
    float sc = g[j] * rsqrtf(fmaxf(var, 0.f) + 1e-3f);
    float v = (acc - m) * sc + be[j];
    out[j * BB + b] = fmaxf(v, 0.f);
}

// ---------------- output layer + softmax (LDS reductions) ----------------
__global__ __launch_bounds__(64) void k_out(const float* __restrict__ ht2, const float* __restrict__ Wout,
                                            const float* __restrict__ bout, float* __restrict__ outp) {
    __shared__ float sm[64];
    int b = blockIdx.x, o = threadIdx.x;
    float acc = 0.f;
    if (o < 40) {
        acc = bout[o];
        for (int k = 0; k < 256; k++) acc = fmaf(ht2[k * BB + b], Wout[k * 40 + o], acc);
    }
    sm[o] = (o < 40) ? acc : -3.0e38f;
    __syncthreads();
    for (int s = 32; s > 0; s >>= 1) {
        if (o < s) sm[o] = fmaxf(sm[o], sm[o + s]);
        __syncthreads();
    }
    float m = sm[0];
    __syncthreads();
    const float L2E = 1.4426950408889634f;
    float e = (o < 40) ? exp2f((acc - m) * L2E) : 0.f;
    sm[o] = e;
    __syncthreads();
    for (int s = 32; s > 0; s >>= 1) {
        if (o < s) sm[o] += sm[o + s];
        __syncthreads();
    }
    if (o < 40) outp[b * 40 + o] = e / sm[0];
}

// ---------------- workspace layout (float offsets) ----------------
#define OFF_PBUF 0          // 4*3*64*512   = 393216
#define OFF_DG0T 393216     // 36*1024      = 36864
#define OFF_RS0 430080      // 1024
#define OFF_DET1 431104     // 165*1024     = 168960
#define OFF_DET2 600064     // 84*1024      = 86016
#define OFF_YQ 686080       // 64*64*1024   = 4194304
#define OFF_YT1 4880384     // 64*165*16    = 168960
#define OFF_YT2 5049344     // 64*84*32     = 172032
#define OFF_YT3 5221376     // 64*84*64     = 344064
#define OFF_HT0 5565440     // 256*64
#define OFF_HT1 5581824     // 512*64
#define OFF_HT2 5614592     // 256*64
#define OFF_STATS 5630976   // 224

extern "C" void kernel_launch(void* const* d_in, const int* in_sizes, int n_in,
                              void* d_out, int out_size, void* d_ws, size_t ws_size,
                              hipStream_t stream) {
    const float* x = (const float*)d_in[0];
    const float* shell_dirs = (const float*)d_in[1];
    const float* A_sh = (const float*)d_in[2];
    const float* D_eval0 = (const float*)d_in[3];
    const float* D_eval1 = (const float*)d_in[4];
    const float* D_eval2 = (const float*)d_in[5];
    const float* D_coef1 = (const float*)d_in[6];
    const float* D_coef2 = (const float*)d_in[7];
    const float* D_coef_last = (const float*)d_in[8];
    const float* W0 = (const float*)d_in[9];
    const float* b0 = (const float*)d_in[10];
    const float* W1 = (const float*)d_in[11];
    const float* b1 = (const float*)d_in[12];
    const float* W2 = (const float*)d_in[13];
    const float* b2 = (const float*)d_in[14];
    const float* g0 = (const float*)d_in[15];
    const float* be0 = (const float*)d_in[16];
    const float* g1 = (const float*)d_in[17];
    const float* be1 = (const float*)d_in[18];
    const float* g2 = (const float*)d_in[19];
    const float* be2 = (const float*)d_in[20];
    const float* Wfc1 = (const float*)d_in[21];
    const float* bfc1 = (const float*)d_in[22];
    const float* gfc1 = (const float*)d_in[23];
    const float* befc1 = (const float*)d_in[24];
    const float* Wfc2 = (const float*)d_in[25];
    const float* bfc2 = (const float*)d_in[26];
    const float* gfc2 = (const float*)d_in[27];
    const float* befc2 = (const float*)d_in[28];
    const float* Wout = (const float*)d_in[29];
    const float* bout = (const float*)d_in[30];
    float* out = (float*)d_out;

    float* ws = (float*)d_ws;
    float* pbuf = ws + OFF_PBUF;
    float* Dg0t = ws + OFF_DG0T;
    float* rs0 = ws + OFF_RS0;
    float* Det1 = ws + OFF_DET1;
    float* Det2 = ws + OFF_DET2;
    float* yq = ws + OFF_YQ;
    float* yt1 = ws + OFF_YT1;
    float* yt2 = ws + OFF_YT2;
    float* yt3 = ws + OFF_YT3;
    float* ht0 = ws + OFF_HT0;
    float* ht1 = ws + OFF_HT1;
    float* ht2 = ws + OFF_HT2;
    float* stats = ws + OFF_STATS;
    float* stats0 = stats;       // 32
    float* stats1 = stats + 32;  // 64
    float* stats2 = stats + 96;  // 128

    k_prep<<<357, 256, 0, stream>>>(D_eval0, D_eval1, D_eval2, Dg0t, rs0, Det1, Det2, stats);
    k_shells<<<dim3(BB, 3, NCH), 256, 0, stream>>>(x, shell_dirs, pbuf);
    k_eval0<<<dim3(4, BB), 256, 0, stream>>>(pbuf, A_sh, W0, b0, Dg0t, rs0, yq, stats0);
    k_coef<165, 16><<<dim3(11, BB), 256, 0, stream>>>(yq, D_coef1, stats0, g0, be0, yt1);
    k_eval<165, 16, 32><<<dim3(4, BB, 2), 256, 0, stream>>>(yt1, W1, b1, Det1, yq, stats1);
    k_coef<84, 32><<<dim3(6, BB), 256, 0, stream>>>(yq, D_coef2, stats1, g1, be1, yt2);
    k_eval<84, 32, 64><<<dim3(4, BB, 4), 256, 0, stream>>>(yt2, W2, b2, Det2, yq, stats2);
    k_coef<84, 64><<<dim3(6, BB), 256, 0, stream>>>(yq, D_coef_last, stats2, g2, be2, yt3);
    k_norms<<<BB, 256, 0, stream>>>(yt3, ht0);
    k_fc<256, 512><<<64, 512, 0, stream>>>(ht0, Wfc1, bfc1, gfc1, befc1, ht1);
    k_fc<512, 256><<<32, 512, 0, stream>>>(ht1, Wfc2, bfc2, gfc2, befc2, ht2);
    k_out<<<BB, 64, 0, stream>>>(ht2, Wout, bout, out);
}